// Round 10
// baseline (3207.309 us; speedup 1.0000x reference)
//
#include <hip/hip_runtime.h>
#include <hip/hip_bf16.h>
#include <stdint.h>

// ---------------------------------------------------------------------------
// B=16, N=1024, D=256, M=128, C=8192. fp32 in/out, bf16 MFMA internally.
// Output: 3 x [B,N,D] fp32 concatenated.
// Attention fully fused (flash-style, ping-pong pipelined): S never in HBM.
// ---------------------------------------------------------------------------

namespace {
constexpr int B_ = 16;
constexpr int N_ = 1024;
constexpr int D_ = 256;
constexpr int M_ = 128;
constexpr int C_ = 8192;
constexpr int BN_ = B_ * N_;                       // 16384
constexpr long long BND_ = (long long)BN_ * D_;    // 4,194,304 elems
constexpr int NB_ = N_ * B_;                       // 16384
constexpr int LDA_S = 40;                          // K-loop LDS stride (shorts)
constexpr int EPI_S = 68;                          // epilogue LDS stride (floats)
}

typedef short bf16x8_t __attribute__((ext_vector_type(8)));
typedef float f32x4_t __attribute__((ext_vector_type(4)));
typedef unsigned short u16x8_t __attribute__((ext_vector_type(8)));

#define DEV static __device__ __forceinline__
DEV float bf2f(unsigned short u) { return __uint_as_float((unsigned)u << 16); }
DEV unsigned short f2bf_bits(float x) { return __builtin_bit_cast(unsigned short, __float2bfloat16(x)); }

// ---------------------------------------------------------------------------
// NT bf16 MFMA GEMM, 128x128 tile, BK=32, 4 waves, LDS-transposed epilogue.
// epi: 0 = fp32 C = v (v = acc*scale)
//      1 = bf16 C = v + bias[col]
//      2 = fp32 C = relu(v + bias[col] + add0[idx] + add1[idx])
//      4 = bf16 C = v + bias[col]*scale      (i.e. (acc+bias)*scale)
// ---------------------------------------------------------------------------
__global__ __launch_bounds__(256) void gemm_nt_kernel(
    const __hip_bfloat16* __restrict__ A0, const __hip_bfloat16* __restrict__ A1,
    int lda, long long sA,
    const __hip_bfloat16* __restrict__ B0, const __hip_bfloat16* __restrict__ B1,
    int ldb, long long sB,
    void* __restrict__ Cv, int ldc, long long sC, long long cOff, long long pieceCs,
    int K, int kPiece, int zBatches,
    float scale, const float* __restrict__ bias,
    const float* __restrict__ add0, const float* __restrict__ add1,
    int epi)
{
    __shared__ __align__(16) char smem[20480];
    short* smA = (short*)smem;
    short* smB = (short*)(smem + 10240);

    const int tid = threadIdx.x;
    const int wid = tid >> 6;
    const int lane = tid & 63;
    const int z = blockIdx.z;
    const int batch = z % zBatches;
    const int rem = z / zBatches;
    const int pi = rem & 1;
    const int kh = rem >> 1;

    const short* Ab = (const short*)(pi ? A1 : A0) + (size_t)batch * sA
                    + (size_t)blockIdx.x * 128 * lda + (size_t)kh * kPiece;
    const short* Bb = (const short*)(pi ? B1 : B0) + (size_t)batch * sB
                    + (size_t)blockIdx.y * 128 * ldb + (size_t)kh * kPiece;

    const int wm = (wid >> 1) * 64;
    const int wn = (wid & 1) * 64;
    const int fr = lane & 15;
    const int kq = (lane >> 4) * 8;
    const int sr = tid >> 2;
    const int sc = (tid & 3) * 8;

    f32x4_t acc[4][4] = {};
    int4 avv[2], bvv[2];
#pragma unroll
    for (int h = 0; h < 2; h++) {
        const int row = h * 64 + sr;
        avv[h] = *(const int4*)(Ab + (size_t)row * lda + sc);
        bvv[h] = *(const int4*)(Bb + (size_t)row * ldb + sc);
    }

    for (int k0 = 0; k0 < K; k0 += 32) {
        __syncthreads();
#pragma unroll
        for (int h = 0; h < 2; h++) {
            const int row = h * 64 + sr;
            *(int4*)&smA[row * LDA_S + sc] = avv[h];
            *(int4*)&smB[row * LDA_S + sc] = bvv[h];
        }
        __syncthreads();

        const int kn = k0 + 32;
        if (kn < K) {
#pragma unroll
            for (int h = 0; h < 2; h++) {
                const int row = h * 64 + sr;
                avv[h] = *(const int4*)(Ab + (size_t)row * lda + (kn + sc));
                bvv[h] = *(const int4*)(Bb + (size_t)row * ldb + (kn + sc));
            }
        }

        bf16x8_t af[4], bfv[4];
#pragma unroll
        for (int i = 0; i < 4; i++)
            af[i] = *(const bf16x8_t*)&smA[(wm + i * 16 + fr) * LDA_S + kq];
#pragma unroll
        for (int j = 0; j < 4; j++)
            bfv[j] = *(const bf16x8_t*)&smB[(wn + j * 16 + fr) * LDA_S + kq];
#pragma unroll
        for (int i = 0; i < 4; i++)
#pragma unroll
            for (int j = 0; j < 4; j++)
                acc[i][j] = __builtin_amdgcn_mfma_f32_16x16x32_bf16(af[i], bfv[j], acc[i][j], 0, 0, 0);
    }

    float* lts = (float*)smem + wid * (16 * EPI_S);
    const int r_ = lane >> 4;
#pragma unroll
    for (int i = 0; i < 4; i++) {
        __syncthreads();
#pragma unroll
        for (int j = 0; j < 4; j++)
#pragma unroll
            for (int r = 0; r < 4; r++)
                lts[(r_ * 4 + r) * EPI_S + j * 16 + fr] = acc[i][j][r] * scale;
        __syncthreads();
#pragma unroll
        for (int t = 0; t < 4; t++) {
            const int lrow = t * 4 + r_;
            const f32x4_t v4 = *(const f32x4_t*)&lts[lrow * EPI_S + fr * 4];
            const int row = blockIdx.x * 128 + wm + i * 16 + lrow;
            const int col = blockIdx.y * 128 + wn + fr * 4;
            const size_t idx = (size_t)batch * sC + (size_t)row * ldc + col;
            const size_t gidx = (size_t)cOff + (size_t)rem * pieceCs + idx;
            if (epi == 0) {
                *(f32x4_t*)((float*)Cv + gidx) = v4;
            } else if (epi == 1 || epi == 4) {
                f32x4_t bb = {0.f, 0.f, 0.f, 0.f};
                if (bias) bb = *(const f32x4_t*)(bias + col);
                const float bs = (epi == 4) ? scale : 1.0f;
                ushort4 pk;
                pk.x = f2bf_bits(v4[0] + bb[0] * bs);
                pk.y = f2bf_bits(v4[1] + bb[1] * bs);
                pk.z = f2bf_bits(v4[2] + bb[2] * bs);
                pk.w = f2bf_bits(v4[3] + bb[3] * bs);
                *(ushort4*)((unsigned short*)Cv + gidx) = pk;
            } else {
                const f32x4_t bb = *(const f32x4_t*)(bias + col);
                const f32x4_t m0 = *(const f32x4_t*)(add0 + idx);
                const f32x4_t m1 = *(const f32x4_t*)(add1 + idx);
                f32x4_t o;
#pragma unroll
                for (int k = 0; k < 4; k++) {
                    float v = v4[k] + bb[k] + m0[k] + m1[k];
                    o[k] = v > 0.0f ? v : 0.0f;
                }
                *(f32x4_t*)((float*)Cv + gidx) = o;
            }
        }
    }
}

// ---------------------------------------------------------------------------
// Fused flash attention, ping-pong pipelined.
// Per block = 64 Q-rows of one (m,batch); both partners sequentially.
// Phases per kv-tile (kt): 8 K-chunks (128 kv x 32 d) then 8 V-half-chunks
// (128 d x 32 kv) — all identical 128x32 stages into a 2x10KB ping-pong
// buffer. One barrier per phase; next chunk prefetched into registers
// before the MFMA burst (latency overlap, incl. over the softmax).
// Msg[p][m][b][n][d] fp32 = softmax(Q_m K_p^T /16) @ V_p
// ---------------------------------------------------------------------------
__global__ __launch_bounds__(256) void flash_attn_kernel(
    const __hip_bfloat16* __restrict__ Qall,   // [3][16][1024][256] bf16, pre-scaled by 1/16
    const __hip_bfloat16* __restrict__ Kall,   // [3][16][1024][256] bf16
    const __hip_bfloat16* __restrict__ Vt,     // [3][16][256][1024] bf16
    float* __restrict__ Msg)                   // [2][3][16][1024][256] fp32
{
    __shared__ __align__(16) short smKV[2][128 * 40];    // 2 x 10240 B ping-pong
    __shared__ __align__(16) char  smP[4 * 4352];        // per-wave P / epilogue

    const int tid = threadIdx.x;
    const int w = tid >> 6;
    const int lane = tid & 63;
    const int fr = lane & 15;
    const int qd = lane >> 4;
    const int qt = blockIdx.x, batch = blockIdx.y, m = blockIdx.z;
    const int pn0 = (m == 0) ? 1 : 0;
    const int pn1 = (m == 2) ? 1 : 2;

    short* Pw = (short*)(smP + w * 4352);
    float* Ew = (float*)(smP + w * 4352);

    // Q fragments: A[m=fr][k=qd*8+j] for 8 d-chunks, wave rows qt*64+w*16+fr
    const size_t qrow = ((size_t)(m * 16 + batch) * 1024) + qt * 64 + w * 16 + fr;
    const short* qp = (const short*)Qall + qrow * 256 + qd * 8;
    bf16x8_t qa[8];
#pragma unroll
    for (int c = 0; c < 8; c++) qa[c] = *(const bf16x8_t*)(qp + c * 32);

    const int sr2 = tid >> 2;            // staging row 0..63 (plus +64)
    const int sc2 = (tid & 3) * 8;       // staging short-col

    for (int p = 0; p < 2; p++) {
        const int pn = p == 0 ? pn0 : pn1;
        const short* Kb = (const short*)Kall + ((size_t)(pn * 16 + batch) * 1024) * 256;
        const short* Vb = (const short*)Vt + ((size_t)(pn * 16 + batch) * 256) * 1024;
        f32x4_t Op[16] = {};
        f32x4_t S[8];
        float mrun[4] = {-1e30f, -1e30f, -1e30f, -1e30f};
        float lrun[4] = {0.f, 0.f, 0.f, 0.f};

        // phase -> global source for the 128x32 chunk (this thread's 16B)
        auto srcptr = [&](int phase, int row) -> const short* {
            const int kt = phase >> 4, pp = phase & 15;
            if (pp < 8)                                   // K chunk: rows=kv, cols=d
                return Kb + (size_t)(kt * 128 + row) * 256 + pp * 32 + sc2;
            const int q = pp - 8, kc = q >> 1, h = q & 1; // V half: rows=d, cols=kv
            return Vb + (size_t)(h * 128 + row) * 1024 + kt * 128 + kc * 32 + sc2;
        };

        int4 st0 = *(const int4*)srcptr(0, sr2);
        int4 st1 = *(const int4*)srcptr(0, sr2 + 64);

        for (int phase = 0; phase < 128; phase++) {
            const int buf = phase & 1;
            const int pp = phase & 15;
            *(int4*)&smKV[buf][sr2 * 40 + sc2] = st0;
            *(int4*)&smKV[buf][(sr2 + 64) * 40 + sc2] = st1;
            if (pp == 0) {
                const f32x4_t zz = {0.f, 0.f, 0.f, 0.f};
#pragma unroll
                for (int f = 0; f < 8; f++) S[f] = zz;
            }
            __syncthreads();
            if (phase < 127) {                     // prefetch next chunk (overlaps MFMA+softmax)
                st0 = *(const int4*)srcptr(phase + 1, sr2);
                st1 = *(const int4*)srcptr(phase + 1, sr2 + 64);
            }
            if (pp < 8) {
                // ---- S += Q_dc K_dc^T ----
#pragma unroll
                for (int f = 0; f < 8; f++) {
                    bf16x8_t kb = *(const bf16x8_t*)&smKV[buf][(f * 16 + fr) * 40 + qd * 8];
                    S[f] = __builtin_amdgcn_mfma_f32_16x16x32_bf16(qa[pp], kb, S[f], 0, 0, 0);
                }
                if (pp == 7) {
                    // ---- online softmax (rows = qd*4+r, cols = f*16+fr) ----
                    float alpha[4], tsum[4];
#pragma unroll
                    for (int r = 0; r < 4; r++) {
                        float mx = S[0][r];
#pragma unroll
                        for (int f = 1; f < 8; f++) mx = fmaxf(mx, S[f][r]);
#pragma unroll
                        for (int o = 1; o < 16; o <<= 1) mx = fmaxf(mx, __shfl_xor(mx, o));
                        const float mnew = fmaxf(mrun[r], mx);
                        alpha[r] = __expf(mrun[r] - mnew);
                        mrun[r] = mnew;
                        tsum[r] = 0.0f;
                    }
#pragma unroll
                    for (int f = 0; f < 8; f++) {
#pragma unroll
                        for (int r = 0; r < 4; r++) {
                            const float pv = __expf(S[f][r] - mrun[r]);
                            tsum[r] += pv;
                            Pw[(qd * 4 + r) * 136 + f * 16 + fr] = (short)f2bf_bits(pv);
                        }
                    }
#pragma unroll
                    for (int r = 0; r < 4; r++) {
                        float s = tsum[r];
#pragma unroll
                        for (int o = 1; o < 16; o <<= 1) s += __shfl_xor(s, o);
                        lrun[r] = lrun[r] * alpha[r] + s;
                    }
#pragma unroll
                    for (int df = 0; df < 16; df++)
#pragma unroll
                        for (int r = 0; r < 4; r++) Op[df][r] *= alpha[r];
                }
            } else {
                // ---- O += P @ V (one d-half, one 32-wide kv chunk) ----
                const int q = pp - 8, kc = q >> 1, h = q & 1;
                const bf16x8_t pa = *(const bf16x8_t*)&Pw[fr * 136 + kc * 32 + qd * 8];
#pragma unroll
                for (int dfl = 0; dfl < 8; dfl++) {
                    bf16x8_t vb = *(const bf16x8_t*)&smKV[buf][(dfl * 16 + fr) * 40 + qd * 8];
                    Op[h * 8 + dfl] =
                        __builtin_amdgcn_mfma_f32_16x16x32_bf16(pa, vb, Op[h * 8 + dfl], 0, 0, 0);
                }
            }
        }

        // ---- normalize, store Msg piece p via LDS transpose ----
        float invl[4];
#pragma unroll
        for (int r = 0; r < 4; r++) invl[r] = 1.0f / lrun[r];
        float* outb = Msg + ((size_t)p * 3 + m) * BND_ + (size_t)batch * N_ * D_
                    + (size_t)(qt * 64 + w * 16) * D_;
        __syncthreads();
#pragma unroll
        for (int ch = 0; ch < 4; ch++) {
#pragma unroll
            for (int jj = 0; jj < 4; jj++)
#pragma unroll
                for (int r = 0; r < 4; r++)
                    Ew[(qd * 4 + r) * EPI_S + jj * 16 + fr] = Op[ch * 4 + jj][r] * invl[r];
            __syncthreads();
#pragma unroll
            for (int t = 0; t < 4; t++) {
                const int lrow = t * 4 + qd;
                const f32x4_t v4 = *(const f32x4_t*)&Ew[lrow * EPI_S + fr * 4];
                *(f32x4_t*)(outb + (size_t)lrow * D_ + ch * 64 + fr * 4) = v4;
            }
            __syncthreads();
        }
    }
}

// ---------------------------------------------------------------------------
// Weight convert+transpose, all 5 weights in one dispatch (z selects).
// ---------------------------------------------------------------------------
__global__ __launch_bounds__(256) void wt_transpose_kernel(
    const float* __restrict__ W0, const float* __restrict__ W1,
    const float* __restrict__ W2, const float* __restrict__ W3,
    const float* __restrict__ W4, __hip_bfloat16* __restrict__ out)
{
    const int z = blockIdx.z;
    const float* in = z == 0 ? W0 : z == 1 ? W1 : z == 2 ? W2 : z == 3 ? W3 : W4;
    __hip_bfloat16* o = out + (size_t)z * D_ * D_;
    __shared__ float t[32][33];
    const int r0 = blockIdx.x * 32, c0 = blockIdx.y * 32;
    const int tx = threadIdx.x & 31, ty = threadIdx.x >> 5;
#pragma unroll
    for (int k = 0; k < 4; k++) {
        int r = ty + k * 8;
        t[r][tx] = in[(size_t)(r0 + r) * D_ + (c0 + tx)];
    }
    __syncthreads();
#pragma unroll
    for (int k = 0; k < 4; k++) {
        int r = ty + k * 8;
        o[(size_t)(c0 + r) * D_ + (r0 + tx)] = __float2bfloat16(t[tx][r]);
    }
}

// bf16 transpose for V: out[c][r] = in[r][c], batched over z.
__global__ __launch_bounds__(256) void transpose_bf16_kernel(
    const __hip_bfloat16* __restrict__ in, __hip_bfloat16* __restrict__ out,
    int R, int Cc, long long sIn, long long sOut)
{
    __shared__ short t[32][33];
    const size_t bz = blockIdx.z;
    const short* I = (const short*)in + bz * (size_t)sIn;
    short* O = (short*)out + bz * (size_t)sOut;
    const int r0 = blockIdx.x * 32, c0 = blockIdx.y * 32;
    const int tx = threadIdx.x & 31, ty = threadIdx.x >> 5;
#pragma unroll
    for (int k = 0; k < 4; k++) {
        int r = ty + k * 8;
        t[r][tx] = I[(size_t)(r0 + r) * Cc + (c0 + tx)];
    }
    __syncthreads();
#pragma unroll
    for (int k = 0; k < 4; k++) {
        int r = ty + k * 8;
        O[(size_t)(c0 + r) * R + (r0 + tx)] = t[tx][r];
    }
}

// all 3 modality inputs fp32 -> bf16, one dispatch
__global__ void cvt3_kernel(const float* __restrict__ x0, const float* __restrict__ x1,
                            const float* __restrict__ x2, __hip_bfloat16* __restrict__ dst)
{
    const int z = blockIdx.z;
    const float* s = z == 0 ? x0 : z == 1 ? x1 : x2;
    const long long i = (long long)blockIdx.x * 256 + threadIdx.x;
    dst[(size_t)z * BND_ + i] = __float2bfloat16(s[i]);
}

__global__ void zero_kernel(float* __restrict__ p, int n)
{
    const int i = blockIdx.x * 256 + threadIdx.x;
    if (i < n) p[i] = 0.0f;
}

// ---------------------------------------------------------------------------
// Hypergraph pipeline, batched over 3 modalities via blockIdx.z
// ---------------------------------------------------------------------------
__global__ void hg_count_kernel(const int* __restrict__ i0, const int* __restrict__ i1,
                                const int* __restrict__ i2,
                                int* __restrict__ Ddeg, int* __restrict__ Edeg)
{
    const int z = blockIdx.z;
    const int* idx = z == 0 ? i0 : z == 1 ? i1 : i2;
    const int c = blockIdx.x * 256 + threadIdx.x;
    atomicAdd(&Ddeg[z * N_ + idx[c]], 1);
    atomicAdd(&Edeg[z * M_ + idx[C_ + c]], 1);
}

__global__ __launch_bounds__(1024) void hg_scan_kernel(
    const int* __restrict__ deg, int* __restrict__ offs,
    float* __restrict__ inv, int* __restrict__ cnt, int len)
{
    const int z = blockIdx.z;
    deg += z * len; offs += z * (len + 1); inv += z * len; cnt += z * len;
    __shared__ int tmp[1024];
    const int t = threadIdx.x;
    const int v = deg[t];
    tmp[t] = v;
    __syncthreads();
    for (int o = 1; o < len; o <<= 1) {
        int x = (t >= o) ? tmp[t - o] : 0;
        __syncthreads();
        tmp[t] += x;
        __syncthreads();
    }
    offs[t] = tmp[t] - v;
    if (t == len - 1) offs[len] = tmp[t];
    inv[t] = (v > 0) ? (1.0f / (float)v) : 0.0f;
    cnt[t] = 0;
}

__global__ void hg_fill_kernel(const int* __restrict__ i0, const int* __restrict__ i1,
                               const int* __restrict__ i2,
                               const int* __restrict__ noffs, const int* __restrict__ eoffs,
                               int* __restrict__ ncnt, int* __restrict__ ecnt,
                               int* __restrict__ nord, int* __restrict__ eord)
{
    const int z = blockIdx.z;
    const int* nidx = z == 0 ? i0 : z == 1 ? i1 : i2;
    const int* eidx = nidx + C_;
    noffs += z * (N_ + 1); eoffs += z * (M_ + 1);
    ncnt += z * N_; ecnt += z * M_; nord += z * C_; eord += z * C_;
    const int c = blockIdx.x * 256 + threadIdx.x;
    const int nd = nidx[c], ed = eidx[c];
    const int p1 = atomicAdd(&ncnt[nd], 1);
    nord[noffs[nd] + p1] = c;
    const int p2 = atomicAdd(&ecnt[ed], 1);
    eord[eoffs[ed] + p2] = c;
}

// s1/s2 from bf16 xp; one wave per (md,b,n)
__global__ __launch_bounds__(64) void hg_s12_kernel(
    const unsigned short* __restrict__ Xp, const float* __restrict__ att,
    float* __restrict__ s1, float* __restrict__ s2)
{
    const int z = blockIdx.z;
    const int bid = blockIdx.x;
    const int b = bid >> 10;
    const int n = bid & (N_ - 1);
    const int lane = threadIdx.x;
    const unsigned short* xr = Xp + (size_t)z * BND_ + (size_t)(b * N_ + n) * D_;
    const ushort4 u = ((const ushort4*)xr)[lane];
    const float4 a1 = ((const float4*)att)[lane];
    const float4 a2 = ((const float4*)(att + D_))[lane];
    float d1 = bf2f(u.x) * a1.x + bf2f(u.y) * a1.y + bf2f(u.z) * a1.z + bf2f(u.w) * a1.w;
    float d2 = bf2f(u.x) * a2.x + bf2f(u.y) * a2.y + bf2f(u.z) * a2.z + bf2f(u.w) * a2.w;
#pragma unroll
    for (int o = 32; o > 0; o >>= 1) { d1 += __shfl_down(d1, o); d2 += __shfl_down(d2, o); }
    if (lane == 0) { s1[z * NB_ + n * 16 + b] = d1; s2[z * NB_ + n * 16 + b] = d2; }
}

// edge_s2[m,b]: atomic-free, grid (M_,1,3), 16 pos x 16 b LDS reduce.
__global__ __launch_bounds__(256) void hg_edge_s2_kernel(
    const int* __restrict__ i0, const int* __restrict__ i1, const int* __restrict__ i2,
    const int* __restrict__ eoffs, const int* __restrict__ eord,
    const float* __restrict__ s2, float* __restrict__ edge_s2)
{
    const int z = blockIdx.z;
    const int* nidx = z == 0 ? i0 : z == 1 ? i1 : i2;
    eoffs += z * (M_ + 1); eord += z * C_;
    s2 += z * NB_; edge_s2 += (size_t)z * M_ * 16;

    const int m = blockIdx.x;
    const int pos = threadIdx.x >> 4;
    const int b = threadIdx.x & 15;
    const int base = eoffs[m];
    const int len = eoffs[m + 1] - base;
    float acc = 0.0f;
#pragma unroll 4
    for (int i = pos; i < len; i += 16) {
        int c = eord[base + i];
        acc += s2[nidx[c] * 16 + b];
    }
    __shared__ float red[16][16];
    red[pos][b] = acc;
    __syncthreads();
    for (int s = 8; s > 0; s >>= 1) {
        if (pos < s) red[pos][b] += red[pos + s][b];
        __syncthreads();
    }
    if (pos == 0) edge_s2[m * 16 + b] = red[0][b];
}

__global__ __launch_bounds__(256) void hg_node_softmax_kernel(
    const int* __restrict__ i0, const int* __restrict__ i1, const int* __restrict__ i2,
    const int* __restrict__ noffs, const int* __restrict__ nord,
    const float* __restrict__ s1, const float* __restrict__ edge_s2,
    float* __restrict__ ee, float* __restrict__ inv_sum)
{
    const int z = blockIdx.z;
    const int* eidx = (z == 0 ? i0 : z == 1 ? i1 : i2) + C_;
    noffs += z * (N_ + 1); nord += z * C_;
    s1 += z * NB_; edge_s2 += (size_t)z * M_ * 16;
    ee += (size_t)z * C_ * 16; inv_sum += z * NB_;

    const int n = blockIdx.x;
    const int base = noffs[n];
    const int len = noffs[n + 1] - base;
    if (len == 0) return;
    const int cp = threadIdx.x >> 4;
    const int b = threadIdx.x & 15;
    __shared__ float red[16][16];
    const float s1nb = s1[n * 16 + b];

    float mx = -1e30f;
    for (int i = cp; i < len; i += 16) {
        int c = nord[base + i];
        float e = s1nb + edge_s2[eidx[c] * 16 + b];
        e = e > 0.0f ? e : 0.2f * e;      // leaky_relu 0.2
        mx = fmaxf(mx, e);
    }
    red[cp][b] = mx;
    __syncthreads();
    for (int s = 8; s > 0; s >>= 1) {
        if (cp < s) red[cp][b] = fmaxf(red[cp][b], red[cp + s][b]);
        __syncthreads();
    }
    mx = red[0][b];
    __syncthreads();

    float sm = 0.0f;
    for (int i = cp; i < len; i += 16) {
        int c = nord[base + i];
        float e = s1nb + edge_s2[eidx[c] * 16 + b];
        e = e > 0.0f ? e : 0.2f * e;
        float ex = __expf(e - mx);
        ee[c * 16 + b] = ex;
        sm += ex;
    }
    red[cp][b] = sm;
    __syncthreads();
    for (int s = 8; s > 0; s >>= 1) {
        if (cp < s) red[cp][b] += red[cp + s][b];
        __syncthreads();
    }
    if (cp == 0) inv_sum[n * 16 + b] = 1.0f / (red[0][b] + 1e-16f);
}

// Pack sorted-order gather arrays (kills dependent chains in xedge/xnode).
__global__ __launch_bounds__(256) void hg_pack_kernel(
    const int* __restrict__ i0, const int* __restrict__ i1, const int* __restrict__ i2,
    const int* __restrict__ nord, const int* __restrict__ eord,
    const float* __restrict__ ee, const float* __restrict__ inv_sum,
    int* __restrict__ EmS, int* __restrict__ NnS,
    float* __restrict__ CoefN, float* __restrict__ CoefE)
{
    const int z = blockIdx.z;
    const int* nidx = z == 0 ? i0 : z == 1 ? i1 : i2;
    const int* eidx = nidx + C_;
    nord += z * C_; eord += z * C_;
    ee += (size_t)z * C_ * 16; inv_sum += z * NB_;
    EmS += z * C_; NnS += z * C_;
    CoefN += (size_t)z * C_ * 16; CoefE += (size_t)z * C_ * 16;

    const int gid = blockIdx.x * 256 + threadIdx.x;   // C*16
    const int i = gid >> 4, b = gid & 15;
    const int c1 = nord[i], c2 = eord[i];
    const int n1 = nidx[c1], n2 = nidx[c2];
    if (b == 0) { EmS[i] = eidx[c1]; NnS[i] = n2; }
    CoefN[i * 16 + b] = ee[c1 * 16 + b] * inv_sum[n1 * 16 + b];
    CoefE[i * 16 + b] = ee[c2 * 16 + b] * inv_sum[n2 * 16 + b];
}

// x_edge[m,b,:] via packed arrays.
__global__ __launch_bounds__(256) void hg_xedge_kernel(
    const int* __restrict__ eoffs, const int* __restrict__ NnS,
    const float* __restrict__ CoefE, const unsigned short* __restrict__ Xp,
    const float* __restrict__ Bnorm, float* __restrict__ x_edge)
{
    const int z = blockIdx.z;
    eoffs += z * (M_ + 1); NnS += z * C_;
    CoefE += (size_t)z * C_ * 16;
    const unsigned short* xp = Xp + (size_t)z * BND_;
    Bnorm += z * M_; x_edge += (size_t)z * M_ * B_ * D_;

    const int m = blockIdx.x >> 4;
    const int b = blockIdx.x & 15;
    const int d = threadIdx.x;
    const int base = eoffs[m];
    const int len = eoffs[m + 1] - base;
    float acc = 0.0f;
#pragma unroll 4
    for (int i = 0; i < len; i++) {
        const int nn = NnS[base + i];
        const float cf = CoefE[(size_t)(base + i) * 16 + b];
        acc += cf * bf2f(xp[(size_t)(b * N_ + nn) * D_ + d]);
    }
    x_edge[((size_t)(m * 16 + b)) * D_ + d] = Bnorm[m] * acc;
}

// h[b,n,:] via packed arrays.
__global__ __launch_bounds__(256) void hg_xnode_kernel(
    const int* __restrict__ noffs, const int* __restrict__ EmS,
    const float* __restrict__ CoefN, const float* __restrict__ x_edge,
    const float* __restrict__ Dinv, __hip_bfloat16* __restrict__ Hbf)
{
    const int z = blockIdx.z;
    noffs += z * (N_ + 1); EmS += z * C_;
    CoefN += (size_t)z * C_ * 16;
    x_edge += (size_t)z * M_ * B_ * D_; Dinv += z * N_;
    __hip_bfloat16* hbf = Hbf + (size_t)z * BND_;

    const int n = blockIdx.x >> 4;
    const int b = blockIdx.x & 15;
    const int d = threadIdx.x;
    const int base = noffs[n];
    const int len = noffs[n + 1] - base;
    float acc = 0.0f;
#pragma unroll 4
    for (int i = 0; i < len; i++) {
        const int em = EmS[base + i];
        const float cf = CoefN[(size_t)(base + i) * 16 + b];
        acc += cf * x_edge[((size_t)(em * 16 + b)) * D_ + d];
    }
    hbf[((size_t)(b * N_ + n)) * D_ + d] = __float2bfloat16(Dinv[n] * acc);
}

// ---------------------------------------------------------------------------
// Host
// ---------------------------------------------------------------------------
static inline void launch_gemm(hipStream_t s, dim3 grid,
                               const void* A0, const void* A1, int lda, long long sA,
                               const void* B0, const void* B1, int ldb, long long sB,
                               void* Cv, int ldc, long long sC, long long cOff, long long pieceCs,
                               int K, int kPiece, int zBatches,
                               float scale, const float* bias,
                               const float* a0, const float* a1, int epi)
{
    gemm_nt_kernel<<<grid, 256, 0, s>>>((const __hip_bfloat16*)A0, (const __hip_bfloat16*)A1,
                                        lda, sA,
                                        (const __hip_bfloat16*)B0, (const __hip_bfloat16*)B1,
                                        ldb, sB,
                                        Cv, ldc, sC, cOff, pieceCs, K, kPiece, zBatches,
                                        scale, bias, a0, a1, epi);
}

extern "C" void kernel_launch(void* const* d_in, const int* in_sizes, int n_in,
                              void* d_out, int out_size, void* d_ws, size_t ws_size,
                              hipStream_t stream)
{
    (void)in_sizes; (void)n_in; (void)out_size; (void)ws_size;

    const float* x0 = (const float*)d_in[0];
    const float* x1 = (const float*)d_in[1];
    const float* x2 = (const float*)d_in[2];
    const int* h0 = (const int*)d_in[3];
    const int* h1 = (const int*)d_in[4];
    const int* h2 = (const int*)d_in[5];
    const float* W_hg  = (const float*)d_in[6];
    const float* att_hg= (const float*)d_in[7];
    const float* WQ = (const float*)d_in[8];
    const float* bQ = (const float*)d_in[9];
    const float* WK = (const float*)d_in[10];
    const float* bK = (const float*)d_in[11];
    const float* WV = (const float*)d_in[12];
    const float* bV = (const float*)d_in[13];
    const float* WO = (const float*)d_in[14];
    const float* bO = (const float*)d_in[15];
    float* outp = (float*)d_out;

    char* ws = (char*)d_ws;
    size_t off = 0;
    auto take = [&](size_t bytes) { size_t r = off; off += (bytes + 255) & ~(size_t)255; return r; };

    const size_t oWt   = take((size_t)5 * D_ * D_ * 2);          // 0.63 MB
    const size_t oHbf  = take((size_t)3 * BND_ * 2);             // 24 MB
    const size_t oKall = take((size_t)3 * BND_ * 2);             // 24 MB
    const size_t oVt   = take((size_t)3 * BND_ * 2);             // 24 MB
    const size_t oQall = take((size_t)3 * BND_ * 2);             // 24 MB
    const size_t oBIG  = take((size_t)6 * BND_ * 4);             // 96 MB: Xc+Xp | Vtmp | Msg(2)
    const size_t oXe   = take((size_t)3 * M_ * B_ * D_ * 4);     // 6 MB
    const size_t oEE   = take((size_t)3 * C_ * 16 * 4);
    const size_t oCoefN= take((size_t)3 * C_ * 16 * 4);
    const size_t oCoefE= take((size_t)3 * C_ * 16 * 4);
    const size_t oEmS  = take((size_t)3 * C_ * 4);
    const size_t oNnS  = take((size_t)3 * C_ * 4);
    const size_t oS1   = take((size_t)3 * NB_ * 4);
    const size_t oS2   = take((size_t)3 * NB_ * 4);
    const size_t oInv  = take((size_t)3 * NB_ * 4);
    const size_t oZero = take((size_t)3 * (N_ + M_) * 4);
    const size_t oEs2  = take((size_t)3 * M_ * 16 * 4);
    const size_t oNOffs= take((size_t)3 * (N_ + 1) * 4);
    const size_t oEOffs= take((size_t)3 * (M_ + 1) * 4);
    const size_t oNCnt = take((size_t)3 * N_ * 4);
    const size_t oECnt = take((size_t)3 * M_ * 4);
    const size_t oNOrd = take((size_t)3 * C_ * 4);
    const size_t oEOrd = take((size_t)3 * C_ * 4);
    const size_t oDinv = take((size_t)3 * N_ * 4);
    const size_t oBnorm= take((size_t)3 * M_ * 4);

    __hip_bfloat16* Wt   = (__hip_bfloat16*)(ws + oWt);
    __hip_bfloat16* Hbf  = (__hip_bfloat16*)(ws + oHbf);
    __hip_bfloat16* Kall = (__hip_bfloat16*)(ws + oKall);
    __hip_bfloat16* Vt   = (__hip_bfloat16*)(ws + oVt);
    __hip_bfloat16* Qall = (__hip_bfloat16*)(ws + oQall);
    __hip_bfloat16* Xc   = (__hip_bfloat16*)(ws + oBIG);
    __hip_bfloat16* Xp   = (__hip_bfloat16*)(ws + oBIG + (size_t)3 * BND_ * 2);
    __hip_bfloat16* Vtmp = (__hip_bfloat16*)(ws + oBIG);
    float* Msg  = (float*)(ws + oBIG);
    float* Xe   = (float*)(ws + oXe);
    float* EE   = (float*)(ws + oEE);
    float* CoefN= (float*)(ws + oCoefN);
    float* CoefE= (float*)(ws + oCoefE);
    int*   EmS  = (int*)(ws + oEmS);
    int*   NnS  = (int*)(ws + oNnS);
    float* S1f  = (float*)(ws + oS1);
    float* S2f  = (float*)(ws + oS2);
    float* Inv  = (float*)(ws + oInv);
    int*   Ddeg = (int*)(ws + oZero);
    int*   Edeg = (int*)(ws + oZero + (size_t)3 * N_ * 4);
    float* Es2  = (float*)(ws + oEs2);
    const int zeroWords = 3 * (N_ + M_);
    int*   NOffs = (int*)(ws + oNOffs);
    int*   EOffs = (int*)(ws + oEOffs);
    int*   NCnt  = (int*)(ws + oNCnt);
    int*   ECnt  = (int*)(ws + oECnt);
    int*   NOrd  = (int*)(ws + oNOrd);
    int*   EOrd  = (int*)(ws + oEOrd);
    float* Dinv  = (float*)(ws + oDinv);
    float* Bnorm = (float*)(ws + oBnorm);

    const int WN = D_ * D_;
    __hip_bfloat16* WtHG = Wt;
    __hip_bfloat16* WtQ  = Wt + (size_t)WN;
    __hip_bfloat16* WtK  = Wt + (size_t)2 * WN;
    __hip_bfloat16* WtV  = Wt + (size_t)3 * WN;
    __hip_bfloat16* WtO  = Wt + (size_t)4 * WN;

    // -------- Phase 0: weights (one dispatch) -------------------------------
    wt_transpose_kernel<<<dim3(8, 8, 5), 256, 0, stream>>>(W_hg, WQ, WK, WV, WO, Wt);

    // -------- Phase 1: hypergraph conv, all modalities batched --------------
    cvt3_kernel<<<dim3((unsigned)(BND_ / 256), 1, 3), 256, 0, stream>>>(x0, x1, x2, Xc);
    zero_kernel<<<(zeroWords + 255) / 256, 256, 0, stream>>>((float*)(ws + oZero), zeroWords);
    hg_count_kernel<<<dim3(C_ / 256, 1, 3), 256, 0, stream>>>(h0, h1, h2, Ddeg, Edeg);
    hg_scan_kernel<<<dim3(1, 1, 3), N_, 0, stream>>>(Ddeg, NOffs, Dinv, NCnt, N_);
    hg_scan_kernel<<<dim3(1, 1, 3), M_, 0, stream>>>(Edeg, EOffs, Bnorm, ECnt, M_);
    hg_fill_kernel<<<dim3(C_ / 256, 1, 3), 256, 0, stream>>>(h0, h1, h2, NOffs, EOffs,
                                                             NCnt, ECnt, NOrd, EOrd);
    launch_gemm(stream, dim3(BN_ / 128, D_ / 128, 3),
                Xc, Xc, D_, BND_, WtHG, WtHG, D_, 0,
                Xp, D_, BND_, 0, 0, D_, D_, 3,
                1.0f, nullptr, nullptr, nullptr, 1);
    hg_s12_kernel<<<dim3(BN_, 1, 3), 64, 0, stream>>>((const unsigned short*)Xp, att_hg, S1f, S2f);
    hg_edge_s2_kernel<<<dim3(M_, 1, 3), 256, 0, stream>>>(h0, h1, h2, EOffs, EOrd, S2f, Es2);
    hg_node_softmax_kernel<<<dim3(N_, 1, 3), 256, 0, stream>>>(h0, h1, h2, NOffs, NOrd,
                                                               S1f, Es2, EE, Inv);
    hg_pack_kernel<<<dim3(C_ * 16 / 256, 1, 3), 256, 0, stream>>>(h0, h1, h2, NOrd, EOrd,
                                                                  EE, Inv, EmS, NnS, CoefN, CoefE);
    hg_xedge_kernel<<<dim3(M_ * B_, 1, 3), 256, 0, stream>>>(EOffs, NnS, CoefE,
                                                             (const unsigned short*)Xp, Bnorm, Xe);
    hg_xnode_kernel<<<dim3(N_ * B_, 1, 3), 256, 0, stream>>>(NOffs, EmS, CoefN, Xe, Dinv, Hbf);

    // -------- Phase 2: K, V, Q for all 3 modalities -------------------------
    launch_gemm(stream, dim3(3 * BN_ / 128, D_ / 128, 1),
                Hbf, Hbf, D_, 0, WtK, WtK, D_, 0,
                Kall, D_, 0, 0, 0, D_, D_, 1,
                1.0f, bK, nullptr, nullptr, 1);
    launch_gemm(stream, dim3(3 * BN_ / 128, D_ / 128, 1),
                Hbf, Hbf, D_, 0, WtV, WtV, D_, 0,
                Vtmp, D_, 0, 0, 0, D_, D_, 1,
                1.0f, bV, nullptr, nullptr, 1);
    transpose_bf16_kernel<<<dim3(N_ / 32, D_ / 32, 48), 256, 0, stream>>>(
        Vtmp, Vt, N_, D_, (long long)N_ * D_, (long long)D_ * N_);
    launch_gemm(stream, dim3(3 * BN_ / 128, D_ / 128, 1),
                Hbf, Hbf, D_, 0, WtQ, WtQ, D_, 0,
                Qall, D_, 0, 0, 0, D_, D_, 1,
                0.0625f, bQ, nullptr, nullptr, 4);

    // -------- Phase 3: fused flash attention + output -----------------------
    flash_attn_kernel<<<dim3(N_ / 64, B_, 3), 256, 0, stream>>>(Qall, Kall, Vt, Msg);
    launch_gemm(stream, dim3(BN_ / 128, D_ / 128, 3),
                Hbf, Hbf, D_, BND_, WtO, WtO, D_, 0,
                outp, D_, BND_, 0, 0, D_, D_, 3,
                1.0f, bO, Msg, Msg + (size_t)3 * BND_, 2);
}

// Round 11
// 863.146 us; speedup vs baseline: 3.7158x; 3.7158x over previous
//
#include <hip/hip_runtime.h>
#include <hip/hip_bf16.h>
#include <stdint.h>

// ---------------------------------------------------------------------------
// B=16, N=1024, D=256, M=128, C=8192. fp32 in/out, bf16 MFMA internally.
// Output: 3 x [B,N,D] fp32 concatenated.
// Attention fully fused (flash-style). NOTE: all register-array indices in the
// flash kernel MUST be compile-time (runtime index -> scratch spill, R10: 2.3GB
// of spill writes, 7x regression).
// ---------------------------------------------------------------------------

namespace {
constexpr int B_ = 16;
constexpr int N_ = 1024;
constexpr int D_ = 256;
constexpr int M_ = 128;
constexpr int C_ = 8192;
constexpr int BN_ = B_ * N_;                       // 16384
constexpr long long BND_ = (long long)BN_ * D_;    // 4,194,304 elems
constexpr int NB_ = N_ * B_;                       // 16384
constexpr int LDA_S = 40;                          // K-loop LDS stride (shorts)
constexpr int EPI_S = 68;                          // epilogue LDS stride (floats)
}

typedef short bf16x8_t __attribute__((ext_vector_type(8)));
typedef float f32x4_t __attribute__((ext_vector_type(4)));
typedef unsigned short u16x8_t __attribute__((ext_vector_type(8)));

#define DEV static __device__ __forceinline__
DEV float bf2f(unsigned short u) { return __uint_as_float((unsigned)u << 16); }
DEV unsigned short f2bf_bits(float x) { return __builtin_bit_cast(unsigned short, __float2bfloat16(x)); }

// ---------------------------------------------------------------------------
// NT bf16 MFMA GEMM, 128x128 tile, BK=32, 4 waves, LDS-transposed epilogue.
// epi: 0 = fp32 C = v (v = acc*scale)
//      1 = bf16 C = v + bias[col]
//      2 = fp32 C = relu(v + bias[col] + add0[idx] + add1[idx])
//      4 = bf16 C = v + bias[col]*scale      (i.e. (acc+bias)*scale)
// ---------------------------------------------------------------------------
__global__ __launch_bounds__(256) void gemm_nt_kernel(
    const __hip_bfloat16* __restrict__ A0, const __hip_bfloat16* __restrict__ A1,
    int lda, long long sA,
    const __hip_bfloat16* __restrict__ B0, const __hip_bfloat16* __restrict__ B1,
    int ldb, long long sB,
    void* __restrict__ Cv, int ldc, long long sC, long long cOff, long long pieceCs,
    int K, int kPiece, int zBatches,
    float scale, const float* __restrict__ bias,
    const float* __restrict__ add0, const float* __restrict__ add1,
    int epi)
{
    __shared__ __align__(16) char smem[20480];
    short* smA = (short*)smem;
    short* smB = (short*)(smem + 10240);

    const int tid = threadIdx.x;
    const int wid = tid >> 6;
    const int lane = tid & 63;
    const int z = blockIdx.z;
    const int batch = z % zBatches;
    const int rem = z / zBatches;
    const int pi = rem & 1;
    const int kh = rem >> 1;

    const short* Ab = (const short*)(pi ? A1 : A0) + (size_t)batch * sA
                    + (size_t)blockIdx.x * 128 * lda + (size_t)kh * kPiece;
    const short* Bb = (const short*)(pi ? B1 : B0) + (size_t)batch * sB
                    + (size_t)blockIdx.y * 128 * ldb + (size_t)kh * kPiece;

    const int wm = (wid >> 1) * 64;
    const int wn = (wid & 1) * 64;
    const int fr = lane & 15;
    const int kq = (lane >> 4) * 8;
    const int sr = tid >> 2;
    const int sc = (tid & 3) * 8;

    f32x4_t acc[4][4] = {};
    int4 avv[2], bvv[2];
#pragma unroll
    for (int h = 0; h < 2; h++) {
        const int row = h * 64 + sr;
        avv[h] = *(const int4*)(Ab + (size_t)row * lda + sc);
        bvv[h] = *(const int4*)(Bb + (size_t)row * ldb + sc);
    }

    for (int k0 = 0; k0 < K; k0 += 32) {
        __syncthreads();
#pragma unroll
        for (int h = 0; h < 2; h++) {
            const int row = h * 64 + sr;
            *(int4*)&smA[row * LDA_S + sc] = avv[h];
            *(int4*)&smB[row * LDA_S + sc] = bvv[h];
        }
        __syncthreads();

        const int kn = k0 + 32;
        if (kn < K) {
#pragma unroll
            for (int h = 0; h < 2; h++) {
                const int row = h * 64 + sr;
                avv[h] = *(const int4*)(Ab + (size_t)row * lda + (kn + sc));
                bvv[h] = *(const int4*)(Bb + (size_t)row * ldb + (kn + sc));
            }
        }

        bf16x8_t af[4], bfv[4];
#pragma unroll
        for (int i = 0; i < 4; i++)
            af[i] = *(const bf16x8_t*)&smA[(wm + i * 16 + fr) * LDA_S + kq];
#pragma unroll
        for (int j = 0; j < 4; j++)
            bfv[j] = *(const bf16x8_t*)&smB[(wn + j * 16 + fr) * LDA_S + kq];
#pragma unroll
        for (int i = 0; i < 4; i++)
#pragma unroll
            for (int j = 0; j < 4; j++)
                acc[i][j] = __builtin_amdgcn_mfma_f32_16x16x32_bf16(af[i], bfv[j], acc[i][j], 0, 0, 0);
    }

    float* lts = (float*)smem + wid * (16 * EPI_S);
    const int r_ = lane >> 4;
#pragma unroll
    for (int i = 0; i < 4; i++) {
        __syncthreads();
#pragma unroll
        for (int j = 0; j < 4; j++)
#pragma unroll
            for (int r = 0; r < 4; r++)
                lts[(r_ * 4 + r) * EPI_S + j * 16 + fr] = acc[i][j][r] * scale;
        __syncthreads();
#pragma unroll
        for (int t = 0; t < 4; t++) {
            const int lrow = t * 4 + r_;
            const f32x4_t v4 = *(const f32x4_t*)&lts[lrow * EPI_S + fr * 4];
            const int row = blockIdx.x * 128 + wm + i * 16 + lrow;
            const int col = blockIdx.y * 128 + wn + fr * 4;
            const size_t idx = (size_t)batch * sC + (size_t)row * ldc + col;
            const size_t gidx = (size_t)cOff + (size_t)rem * pieceCs + idx;
            if (epi == 0) {
                *(f32x4_t*)((float*)Cv + gidx) = v4;
            } else if (epi == 1 || epi == 4) {
                f32x4_t bb = {0.f, 0.f, 0.f, 0.f};
                if (bias) bb = *(const f32x4_t*)(bias + col);
                const float bs = (epi == 4) ? scale : 1.0f;
                ushort4 pk;
                pk.x = f2bf_bits(v4[0] + bb[0] * bs);
                pk.y = f2bf_bits(v4[1] + bb[1] * bs);
                pk.z = f2bf_bits(v4[2] + bb[2] * bs);
                pk.w = f2bf_bits(v4[3] + bb[3] * bs);
                *(ushort4*)((unsigned short*)Cv + gidx) = pk;
            } else {
                const f32x4_t bb = *(const f32x4_t*)(bias + col);
                const f32x4_t m0 = *(const f32x4_t*)(add0 + idx);
                const f32x4_t m1 = *(const f32x4_t*)(add1 + idx);
                f32x4_t o;
#pragma unroll
                for (int k = 0; k < 4; k++) {
                    float v = v4[k] + bb[k] + m0[k] + m1[k];
                    o[k] = v > 0.0f ? v : 0.0f;
                }
                *(f32x4_t*)((float*)Cv + gidx) = o;
            }
        }
    }
}

// ---------------------------------------------------------------------------
// Fused flash attention, ping-pong pipelined with COMPILE-TIME phase unroll.
// Per block = 64 Q-rows of one (m,batch); both partners sequentially.
// Per kv-tile kt: 16 phases (8 K-chunks 128x32, then 8 V-half-chunks 128x32)
// into a 2 x 10KB ping-pong buffer; ONE barrier per phase; next chunk
// prefetched into registers right after the barrier (overlaps MFMA+softmax).
// The pp loop is #pragma unroll so qa[pp] / Op[...] indices stay compile-time.
// Msg[p][m][b][n][d] fp32 = softmax(Q_m K_p^T /16) @ V_p
// ---------------------------------------------------------------------------
__global__ __launch_bounds__(256) void flash_attn_kernel(
    const __hip_bfloat16* __restrict__ Qall,   // [3][16][1024][256] bf16, pre-scaled by 1/16
    const __hip_bfloat16* __restrict__ Kall,   // [3][16][1024][256] bf16
    const __hip_bfloat16* __restrict__ Vt,     // [3][16][256][1024] bf16
    float* __restrict__ Msg)                   // [2][3][16][1024][256] fp32
{
    __shared__ __align__(16) short smKV[2][128 * 40];    // 2 x 10240 B ping-pong
    __shared__ __align__(16) char  smP[4 * 4352];        // per-wave P / epilogue

    const int tid = threadIdx.x;
    const int w = tid >> 6;
    const int lane = tid & 63;
    const int fr = lane & 15;
    const int qd = lane >> 4;
    const int qt = blockIdx.x, batch = blockIdx.y, m = blockIdx.z;
    const int pn0 = (m == 0) ? 1 : 0;
    const int pn1 = (m == 2) ? 1 : 2;

    short* Pw = (short*)(smP + w * 4352);
    float* Ew = (float*)(smP + w * 4352);

    // Q fragments: A[m=fr][k=qd*8+j] for 8 d-chunks, wave rows qt*64+w*16+fr
    const size_t qrow = ((size_t)(m * 16 + batch) * 1024) + qt * 64 + w * 16 + fr;
    const short* qp = (const short*)Qall + qrow * 256 + qd * 8;
    bf16x8_t qa[8];
#pragma unroll
    for (int c = 0; c < 8; c++) qa[c] = *(const bf16x8_t*)(qp + c * 32);

    const int sr2 = tid >> 2;            // staging row 0..63 (plus +64)
    const int sc2 = (tid & 3) * 8;       // staging short-col

    for (int p = 0; p < 2; p++) {
        const int pn = p == 0 ? pn0 : pn1;
        const short* Kb = (const short*)Kall + ((size_t)(pn * 16 + batch) * 1024) * 256;
        const short* Vb = (const short*)Vt + ((size_t)(pn * 16 + batch) * 256) * 1024;
        f32x4_t Op[16] = {};
        float mrun[4] = {-1e30f, -1e30f, -1e30f, -1e30f};
        float lrun[4] = {0.f, 0.f, 0.f, 0.f};

        // prologue: K chunk (kt=0, dc=0)
        int4 st0 = *(const int4*)(Kb + (size_t)sr2 * 256 + sc2);
        int4 st1 = *(const int4*)(Kb + (size_t)(sr2 + 64) * 256 + sc2);

        for (int kt = 0; kt < 8; kt++) {
            f32x4_t S[8] = {};
#pragma unroll
            for (int pp = 0; pp < 16; pp++) {              // COMPILE-TIME phases
                short* buf = smKV[pp & 1];                 // kt*16 even -> pp&1
                *(int4*)&buf[sr2 * 40 + sc2] = st0;
                *(int4*)&buf[(sr2 + 64) * 40 + sc2] = st1;
                __syncthreads();
                // prefetch next phase's chunk (registers; overlaps MFMA below)
                if (pp < 7) {                              // next K chunk, same kt
                    st0 = *(const int4*)(Kb + (size_t)(kt * 128 + sr2) * 256 + (pp + 1) * 32 + sc2);
                    st1 = *(const int4*)(Kb + (size_t)(kt * 128 + sr2 + 64) * 256 + (pp + 1) * 32 + sc2);
                } else if (pp < 15) {                      // next V half-chunk
                    const int qn = pp + 1 - 8, kcn = qn >> 1, hn = qn & 1;
                    st0 = *(const int4*)(Vb + (size_t)(hn * 128 + sr2) * 1024 + kt * 128 + kcn * 32 + sc2);
                    st1 = *(const int4*)(Vb + (size_t)(hn * 128 + sr2 + 64) * 1024 + kt * 128 + kcn * 32 + sc2);
                } else if (kt < 7) {                       // next kt, K chunk 0
                    st0 = *(const int4*)(Kb + (size_t)((kt + 1) * 128 + sr2) * 256 + sc2);
                    st1 = *(const int4*)(Kb + (size_t)((kt + 1) * 128 + sr2 + 64) * 256 + sc2);
                }
                if (pp < 8) {
                    // ---- S += Q_pp K_pp^T ----
#pragma unroll
                    for (int f = 0; f < 8; f++) {
                        bf16x8_t kb = *(const bf16x8_t*)&buf[(f * 16 + fr) * 40 + qd * 8];
                        S[f] = __builtin_amdgcn_mfma_f32_16x16x32_bf16(qa[pp], kb, S[f], 0, 0, 0);
                    }
                    if (pp == 7) {
                        // ---- online softmax (rows = qd*4+r, cols = f*16+fr) ----
                        float alpha[4], tsum[4];
#pragma unroll
                        for (int r = 0; r < 4; r++) {
                            float mx = S[0][r];
#pragma unroll
                            for (int f = 1; f < 8; f++) mx = fmaxf(mx, S[f][r]);
#pragma unroll
                            for (int o = 1; o < 16; o <<= 1) mx = fmaxf(mx, __shfl_xor(mx, o));
                            const float mnew = fmaxf(mrun[r], mx);
                            alpha[r] = __expf(mrun[r] - mnew);
                            mrun[r] = mnew;
                            tsum[r] = 0.0f;
                        }
#pragma unroll
                        for (int f = 0; f < 8; f++) {
#pragma unroll
                            for (int r = 0; r < 4; r++) {
                                const float pv = __expf(S[f][r] - mrun[r]);
                                tsum[r] += pv;
                                Pw[(qd * 4 + r) * 136 + f * 16 + fr] = (short)f2bf_bits(pv);
                            }
                        }
#pragma unroll
                        for (int r = 0; r < 4; r++) {
                            float s = tsum[r];
#pragma unroll
                            for (int o = 1; o < 16; o <<= 1) s += __shfl_xor(s, o);
                            lrun[r] = lrun[r] * alpha[r] + s;
                        }
#pragma unroll
                        for (int df = 0; df < 16; df++)
#pragma unroll
                            for (int r = 0; r < 4; r++) Op[df][r] *= alpha[r];
                    }
                } else {
                    // ---- O += P @ V (one d-half, one 32-wide kv chunk) ----
                    const int q = pp - 8, kc = q >> 1, h = q & 1;  // compile-time
                    const bf16x8_t pa = *(const bf16x8_t*)&Pw[fr * 136 + kc * 32 + qd * 8];
#pragma unroll
                    for (int dfl = 0; dfl < 8; dfl++) {
                        bf16x8_t vb = *(const bf16x8_t*)&buf[(dfl * 16 + fr) * 40 + qd * 8];
                        Op[h * 8 + dfl] =
                            __builtin_amdgcn_mfma_f32_16x16x32_bf16(pa, vb, Op[h * 8 + dfl], 0, 0, 0);
                    }
                }
            }
        }

        // ---- normalize, store Msg piece p via LDS transpose ----
        float invl[4];
#pragma unroll
        for (int r = 0; r < 4; r++) invl[r] = 1.0f / lrun[r];
        float* outb = Msg + ((size_t)p * 3 + m) * BND_ + (size_t)batch * N_ * D_
                    + (size_t)(qt * 64 + w * 16) * D_;
        __syncthreads();
#pragma unroll
        for (int ch = 0; ch < 4; ch++) {
#pragma unroll
            for (int jj = 0; jj < 4; jj++)
#pragma unroll
                for (int r = 0; r < 4; r++)
                    Ew[(qd * 4 + r) * EPI_S + jj * 16 + fr] = Op[ch * 4 + jj][r] * invl[r];
            __syncthreads();
#pragma unroll
            for (int t = 0; t < 4; t++) {
                const int lrow = t * 4 + qd;
                const f32x4_t v4 = *(const f32x4_t*)&Ew[lrow * EPI_S + fr * 4];
                *(f32x4_t*)(outb + (size_t)lrow * D_ + ch * 64 + fr * 4) = v4;
            }
            __syncthreads();
        }
    }
}

// ---------------------------------------------------------------------------
// Weight convert+transpose, all 5 weights in one dispatch (z selects).
// ---------------------------------------------------------------------------
__global__ __launch_bounds__(256) void wt_transpose_kernel(
    const float* __restrict__ W0, const float* __restrict__ W1,
    const float* __restrict__ W2, const float* __restrict__ W3,
    const float* __restrict__ W4, __hip_bfloat16* __restrict__ out)
{
    const int z = blockIdx.z;
    const float* in = z == 0 ? W0 : z == 1 ? W1 : z == 2 ? W2 : z == 3 ? W3 : W4;
    __hip_bfloat16* o = out + (size_t)z * D_ * D_;
    __shared__ float t[32][33];
    const int r0 = blockIdx.x * 32, c0 = blockIdx.y * 32;
    const int tx = threadIdx.x & 31, ty = threadIdx.x >> 5;
#pragma unroll
    for (int k = 0; k < 4; k++) {
        int r = ty + k * 8;
        t[r][tx] = in[(size_t)(r0 + r) * D_ + (c0 + tx)];
    }
    __syncthreads();
#pragma unroll
    for (int k = 0; k < 4; k++) {
        int r = ty + k * 8;
        o[(size_t)(c0 + r) * D_ + (r0 + tx)] = __float2bfloat16(t[tx][r]);
    }
}

// bf16 transpose for V: out[c][r] = in[r][c], batched over z.
__global__ __launch_bounds__(256) void transpose_bf16_kernel(
    const __hip_bfloat16* __restrict__ in, __hip_bfloat16* __restrict__ out,
    int R, int Cc, long long sIn, long long sOut)
{
    __shared__ short t[32][33];
    const size_t bz = blockIdx.z;
    const short* I = (const short*)in + bz * (size_t)sIn;
    short* O = (short*)out + bz * (size_t)sOut;
    const int r0 = blockIdx.x * 32, c0 = blockIdx.y * 32;
    const int tx = threadIdx.x & 31, ty = threadIdx.x >> 5;
#pragma unroll
    for (int k = 0; k < 4; k++) {
        int r = ty + k * 8;
        t[r][tx] = I[(size_t)(r0 + r) * Cc + (c0 + tx)];
    }
    __syncthreads();
#pragma unroll
    for (int k = 0; k < 4; k++) {
        int r = ty + k * 8;
        O[(size_t)(c0 + r) * R + (r0 + tx)] = t[tx][r];
    }
}

// all 3 modality inputs fp32 -> bf16, one dispatch
__global__ void cvt3_kernel(const float* __restrict__ x0, const float* __restrict__ x1,
                            const float* __restrict__ x2, __hip_bfloat16* __restrict__ dst)
{
    const int z = blockIdx.z;
    const float* s = z == 0 ? x0 : z == 1 ? x1 : x2;
    const long long i = (long long)blockIdx.x * 256 + threadIdx.x;
    dst[(size_t)z * BND_ + i] = __float2bfloat16(s[i]);
}

__global__ void zero_kernel(float* __restrict__ p, int n)
{
    const int i = blockIdx.x * 256 + threadIdx.x;
    if (i < n) p[i] = 0.0f;
}

// ---------------------------------------------------------------------------
// Hypergraph pipeline, batched over 3 modalities via blockIdx.z
// ---------------------------------------------------------------------------
__global__ void hg_count_kernel(const int* __restrict__ i0, const int* __restrict__ i1,
                                const int* __restrict__ i2,
                                int* __restrict__ Ddeg, int* __restrict__ Edeg)
{
    const int z = blockIdx.z;
    const int* idx = z == 0 ? i0 : z == 1 ? i1 : i2;
    const int c = blockIdx.x * 256 + threadIdx.x;
    atomicAdd(&Ddeg[z * N_ + idx[c]], 1);
    atomicAdd(&Edeg[z * M_ + idx[C_ + c]], 1);
}

__global__ __launch_bounds__(1024) void hg_scan_kernel(
    const int* __restrict__ deg, int* __restrict__ offs,
    float* __restrict__ inv, int* __restrict__ cnt, int len)
{
    const int z = blockIdx.z;
    deg += z * len; offs += z * (len + 1); inv += z * len; cnt += z * len;
    __shared__ int tmp[1024];
    const int t = threadIdx.x;
    const int v = deg[t];
    tmp[t] = v;
    __syncthreads();
    for (int o = 1; o < len; o <<= 1) {
        int x = (t >= o) ? tmp[t - o] : 0;
        __syncthreads();
        tmp[t] += x;
        __syncthreads();
    }
    offs[t] = tmp[t] - v;
    if (t == len - 1) offs[len] = tmp[t];
    inv[t] = (v > 0) ? (1.0f / (float)v) : 0.0f;
    cnt[t] = 0;
}

__global__ void hg_fill_kernel(const int* __restrict__ i0, const int* __restrict__ i1,
                               const int* __restrict__ i2,
                               const int* __restrict__ noffs, const int* __restrict__ eoffs,
                               int* __restrict__ ncnt, int* __restrict__ ecnt,
                               int* __restrict__ nord, int* __restrict__ eord)
{
    const int z = blockIdx.z;
    const int* nidx = z == 0 ? i0 : z == 1 ? i1 : i2;
    const int* eidx = nidx + C_;
    noffs += z * (N_ + 1); eoffs += z * (M_ + 1);
    ncnt += z * N_; ecnt += z * M_; nord += z * C_; eord += z * C_;
    const int c = blockIdx.x * 256 + threadIdx.x;
    const int nd = nidx[c], ed = eidx[c];
    const int p1 = atomicAdd(&ncnt[nd], 1);
    nord[noffs[nd] + p1] = c;
    const int p2 = atomicAdd(&ecnt[ed], 1);
    eord[eoffs[ed] + p2] = c;
}

// s1/s2 from bf16 xp; one wave per (md,b,n)
__global__ __launch_bounds__(64) void hg_s12_kernel(
    const unsigned short* __restrict__ Xp, const float* __restrict__ att,
    float* __restrict__ s1, float* __restrict__ s2)
{
    const int z = blockIdx.z;
    const int bid = blockIdx.x;
    const int b = bid >> 10;
    const int n = bid & (N_ - 1);
    const int lane = threadIdx.x;
    const unsigned short* xr = Xp + (size_t)z * BND_ + (size_t)(b * N_ + n) * D_;
    const ushort4 u = ((const ushort4*)xr)[lane];
    const float4 a1 = ((const float4*)att)[lane];
    const float4 a2 = ((const float4*)(att + D_))[lane];
    float d1 = bf2f(u.x) * a1.x + bf2f(u.y) * a1.y + bf2f(u.z) * a1.z + bf2f(u.w) * a1.w;
    float d2 = bf2f(u.x) * a2.x + bf2f(u.y) * a2.y + bf2f(u.z) * a2.z + bf2f(u.w) * a2.w;
#pragma unroll
    for (int o = 32; o > 0; o >>= 1) { d1 += __shfl_down(d1, o); d2 += __shfl_down(d2, o); }
    if (lane == 0) { s1[z * NB_ + n * 16 + b] = d1; s2[z * NB_ + n * 16 + b] = d2; }
}

// edge_s2[m,b]: atomic-free, grid (M_,1,3), 16 pos x 16 b LDS reduce.
__global__ __launch_bounds__(256) void hg_edge_s2_kernel(
    const int* __restrict__ i0, const int* __restrict__ i1, const int* __restrict__ i2,
    const int* __restrict__ eoffs, const int* __restrict__ eord,
    const float* __restrict__ s2, float* __restrict__ edge_s2)
{
    const int z = blockIdx.z;
    const int* nidx = z == 0 ? i0 : z == 1 ? i1 : i2;
    eoffs += z * (M_ + 1); eord += z * C_;
    s2 += z * NB_; edge_s2 += (size_t)z * M_ * 16;

    const int m = blockIdx.x;
    const int pos = threadIdx.x >> 4;
    const int b = threadIdx.x & 15;
    const int base = eoffs[m];
    const int len = eoffs[m + 1] - base;
    float acc = 0.0f;
#pragma unroll 4
    for (int i = pos; i < len; i += 16) {
        int c = eord[base + i];
        acc += s2[nidx[c] * 16 + b];
    }
    __shared__ float red[16][16];
    red[pos][b] = acc;
    __syncthreads();
    for (int s = 8; s > 0; s >>= 1) {
        if (pos < s) red[pos][b] += red[pos + s][b];
        __syncthreads();
    }
    if (pos == 0) edge_s2[m * 16 + b] = red[0][b];
}

__global__ __launch_bounds__(256) void hg_node_softmax_kernel(
    const int* __restrict__ i0, const int* __restrict__ i1, const int* __restrict__ i2,
    const int* __restrict__ noffs, const int* __restrict__ nord,
    const float* __restrict__ s1, const float* __restrict__ edge_s2,
    float* __restrict__ ee, float* __restrict__ inv_sum)
{
    const int z = blockIdx.z;
    const int* eidx = (z == 0 ? i0 : z == 1 ? i1 : i2) + C_;
    noffs += z * (N_ + 1); nord += z * C_;
    s1 += z * NB_; edge_s2 += (size_t)z * M_ * 16;
    ee += (size_t)z * C_ * 16; inv_sum += z * NB_;

    const int n = blockIdx.x;
    const int base = noffs[n];
    const int len = noffs[n + 1] - base;
    if (len == 0) return;
    const int cp = threadIdx.x >> 4;
    const int b = threadIdx.x & 15;
    __shared__ float red[16][16];
    const float s1nb = s1[n * 16 + b];

    float mx = -1e30f;
    for (int i = cp; i < len; i += 16) {
        int c = nord[base + i];
        float e = s1nb + edge_s2[eidx[c] * 16 + b];
        e = e > 0.0f ? e : 0.2f * e;      // leaky_relu 0.2
        mx = fmaxf(mx, e);
    }
    red[cp][b] = mx;
    __syncthreads();
    for (int s = 8; s > 0; s >>= 1) {
        if (cp < s) red[cp][b] = fmaxf(red[cp][b], red[cp + s][b]);
        __syncthreads();
    }
    mx = red[0][b];
    __syncthreads();

    float sm = 0.0f;
    for (int i = cp; i < len; i += 16) {
        int c = nord[base + i];
        float e = s1nb + edge_s2[eidx[c] * 16 + b];
        e = e > 0.0f ? e : 0.2f * e;
        float ex = __expf(e - mx);
        ee[c * 16 + b] = ex;
        sm += ex;
    }
    red[cp][b] = sm;
    __syncthreads();
    for (int s = 8; s > 0; s >>= 1) {
        if (cp < s) red[cp][b] += red[cp + s][b];
        __syncthreads();
    }
    if (cp == 0) inv_sum[n * 16 + b] = 1.0f / (red[0][b] + 1e-16f);
}

// Pack sorted-order gather arrays (kills dependent chains in xedge/xnode).
__global__ __launch_bounds__(256) void hg_pack_kernel(
    const int* __restrict__ i0, const int* __restrict__ i1, const int* __restrict__ i2,
    const int* __restrict__ nord, const int* __restrict__ eord,
    const float* __restrict__ ee, const float* __restrict__ inv_sum,
    int* __restrict__ EmS, int* __restrict__ NnS,
    float* __restrict__ CoefN, float* __restrict__ CoefE)
{
    const int z = blockIdx.z;
    const int* nidx = z == 0 ? i0 : z == 1 ? i1 : i2;
    const int* eidx = nidx + C_;
    nord += z * C_; eord += z * C_;
    ee += (size_t)z * C_ * 16; inv_sum += z * NB_;
    EmS += z * C_; NnS += z * C_;
    CoefN += (size_t)z * C_ * 16; CoefE += (size_t)z * C_ * 16;

    const int gid = blockIdx.x * 256 + threadIdx.x;   // C*16
    const int i = gid >> 4, b = gid & 15;
    const int c1 = nord[i], c2 = eord[i];
    const int n1 = nidx[c1], n2 = nidx[c2];
    if (b == 0) { EmS[i] = eidx[c1]; NnS[i] = n2; }
    CoefN[i * 16 + b] = ee[c1 * 16 + b] * inv_sum[n1 * 16 + b];
    CoefE[i * 16 + b] = ee[c2 * 16 + b] * inv_sum[n2 * 16 + b];
}

// x_edge[m,b,:] via packed arrays.
__global__ __launch_bounds__(256) void hg_xedge_kernel(
    const int* __restrict__ eoffs, const int* __restrict__ NnS,
    const float* __restrict__ CoefE, const unsigned short* __restrict__ Xp,
    const float* __restrict__ Bnorm, float* __restrict__ x_edge)
{
    const int z = blockIdx.z;
    eoffs += z * (M_ + 1); NnS += z * C_;
    CoefE += (size_t)z * C_ * 16;
    const unsigned short* xp = Xp + (size_t)z * BND_;
    Bnorm += z * M_; x_edge += (size_t)z * M_ * B_ * D_;

    const int m = blockIdx.x >> 4;
    const int b = blockIdx.x & 15;
    const int d = threadIdx.x;
    const int base = eoffs[m];
    const int len = eoffs[m + 1] - base;
    float acc = 0.0f;
#pragma unroll 4
    for (int i = 0; i < len; i++) {
        const int nn = NnS[base + i];
        const float cf = CoefE[(size_t)(base + i) * 16 + b];
        acc += cf * bf2f(xp[(size_t)(b * N_ + nn) * D_ + d]);
    }
    x_edge[((size_t)(m * 16 + b)) * D_ + d] = Bnorm[m] * acc;
}

// h[b,n,:] via packed arrays.
__global__ __launch_bounds__(256) void hg_xnode_kernel(
    const int* __restrict__ noffs, const int* __restrict__ EmS,
    const float* __restrict__ CoefN, const float* __restrict__ x_edge,
    const float* __restrict__ Dinv, __hip_bfloat16* __restrict__ Hbf)
{
    const int z = blockIdx.z;
    noffs += z * (N_ + 1); EmS += z * C_;
    CoefN += (size_t)z * C_ * 16;
    x_edge += (size_t)z * M_ * B_ * D_; Dinv += z * N_;
    __hip_bfloat16* hbf = Hbf + (size_t)z * BND_;

    const int n = blockIdx.x >> 4;
    const int b = blockIdx.x & 15;
    const int d = threadIdx.x;
    const int base = noffs[n];
    const int len = noffs[n + 1] - base;
    float acc = 0.0f;
#pragma unroll 4
    for (int i = 0; i < len; i++) {
        const int em = EmS[base + i];
        const float cf = CoefN[(size_t)(base + i) * 16 + b];
        acc += cf * x_edge[((size_t)(em * 16 + b)) * D_ + d];
    }
    hbf[((size_t)(b * N_ + n)) * D_ + d] = __float2bfloat16(Dinv[n] * acc);
}

// ---------------------------------------------------------------------------
// Host
// ---------------------------------------------------------------------------
static inline void launch_gemm(hipStream_t s, dim3 grid,
                               const void* A0, const void* A1, int lda, long long sA,
                               const void* B0, const void* B1, int ldb, long long sB,
                               void* Cv, int ldc, long long sC, long long cOff, long long pieceCs,
                               int K, int kPiece, int zBatches,
                               float scale, const float* bias,
                               const float* a0, const float* a1, int epi)
{
    gemm_nt_kernel<<<grid, 256, 0, s>>>((const __hip_bfloat16*)A0, (const __hip_bfloat16*)A1,
                                        lda, sA,
                                        (const __hip_bfloat16*)B0, (const __hip_bfloat16*)B1,
                                        ldb, sB,
                                        Cv, ldc, sC, cOff, pieceCs, K, kPiece, zBatches,
                                        scale, bias, a0, a1, epi);
}

extern "C" void kernel_launch(void* const* d_in, const int* in_sizes, int n_in,
                              void* d_out, int out_size, void* d_ws, size_t ws_size,
                              hipStream_t stream)
{
    (void)in_sizes; (void)n_in; (void)out_size; (void)ws_size;

    const float* x0 = (const float*)d_in[0];
    const float* x1 = (const float*)d_in[1];
    const float* x2 = (const float*)d_in[2];
    const int* h0 = (const int*)d_in[3];
    const int* h1 = (const int*)d_in[4];
    const int* h2 = (const int*)d_in[5];
    const float* W_hg  = (const float*)d_in[6];
    const float* att_hg= (const float*)d_in[7];
    const float* WQ = (const float*)d_in[8];
    const float* bQ = (const float*)d_in[9];
    const float* WK = (const float*)d_in[10];
    const float* bK = (const float*)d_in[11];
    const float* WV = (const float*)d_in[12];
    const float* bV = (const float*)d_in[13];
    const float* WO = (const float*)d_in[14];
    const float* bO = (const float*)d_in[15];
    float* outp = (float*)d_out;

    char* ws = (char*)d_ws;
    size_t off = 0;
    auto take = [&](size_t bytes) { size_t r = off; off += (bytes + 255) & ~(size_t)255; return r; };

    const size_t oWt   = take((size_t)5 * D_ * D_ * 2);          // 0.63 MB
    const size_t oHbf  = take((size_t)3 * BND_ * 2);             // 24 MB
    const size_t oKall = take((size_t)3 * BND_ * 2);             // 24 MB
    const size_t oVt   = take((size_t)3 * BND_ * 2);             // 24 MB
    const size_t oQall = take((size_t)3 * BND_ * 2);             // 24 MB
    const size_t oBIG  = take((size_t)6 * BND_ * 4);             // 96 MB: Xc+Xp | Vtmp | Msg(2)
    const size_t oXe   = take((size_t)3 * M_ * B_ * D_ * 4);     // 6 MB
    const size_t oEE   = take((size_t)3 * C_ * 16 * 4);
    const size_t oCoefN= take((size_t)3 * C_ * 16 * 4);
    const size_t oCoefE= take((size_t)3 * C_ * 16 * 4);
    const size_t oEmS  = take((size_t)3 * C_ * 4);
    const size_t oNnS  = take((size_t)3 * C_ * 4);
    const size_t oS1   = take((size_t)3 * NB_ * 4);
    const size_t oS2   = take((size_t)3 * NB_ * 4);
    const size_t oInv  = take((size_t)3 * NB_ * 4);
    const size_t oZero = take((size_t)3 * (N_ + M_) * 4);
    const size_t oEs2  = take((size_t)3 * M_ * 16 * 4);
    const size_t oNOffs= take((size_t)3 * (N_ + 1) * 4);
    const size_t oEOffs= take((size_t)3 * (M_ + 1) * 4);
    const size_t oNCnt = take((size_t)3 * N_ * 4);
    const size_t oECnt = take((size_t)3 * M_ * 4);
    const size_t oNOrd = take((size_t)3 * C_ * 4);
    const size_t oEOrd = take((size_t)3 * C_ * 4);
    const size_t oDinv = take((size_t)3 * N_ * 4);
    const size_t oBnorm= take((size_t)3 * M_ * 4);

    __hip_bfloat16* Wt   = (__hip_bfloat16*)(ws + oWt);
    __hip_bfloat16* Hbf  = (__hip_bfloat16*)(ws + oHbf);
    __hip_bfloat16* Kall = (__hip_bfloat16*)(ws + oKall);
    __hip_bfloat16* Vt   = (__hip_bfloat16*)(ws + oVt);
    __hip_bfloat16* Qall = (__hip_bfloat16*)(ws + oQall);
    __hip_bfloat16* Xc   = (__hip_bfloat16*)(ws + oBIG);
    __hip_bfloat16* Xp   = (__hip_bfloat16*)(ws + oBIG + (size_t)3 * BND_ * 2);
    __hip_bfloat16* Vtmp = (__hip_bfloat16*)(ws + oBIG);
    float* Msg  = (float*)(ws + oBIG);
    float* Xe   = (float*)(ws + oXe);
    float* EE   = (float*)(ws + oEE);
    float* CoefN= (float*)(ws + oCoefN);
    float* CoefE= (float*)(ws + oCoefE);
    int*   EmS  = (int*)(ws + oEmS);
    int*   NnS  = (int*)(ws + oNnS);
    float* S1f  = (float*)(ws + oS1);
    float* S2f  = (float*)(ws + oS2);
    float* Inv  = (float*)(ws + oInv);
    int*   Ddeg = (int*)(ws + oZero);
    int*   Edeg = (int*)(ws + oZero + (size_t)3 * N_ * 4);
    float* Es2  = (float*)(ws + oEs2);
    const int zeroWords = 3 * (N_ + M_);
    int*   NOffs = (int*)(ws + oNOffs);
    int*   EOffs = (int*)(ws + oEOffs);
    int*   NCnt  = (int*)(ws + oNCnt);
    int*   ECnt  = (int*)(ws + oECnt);
    int*   NOrd  = (int*)(ws + oNOrd);
    int*   EOrd  = (int*)(ws + oEOrd);
    float* Dinv  = (float*)(ws + oDinv);
    float* Bnorm = (float*)(ws + oBnorm);

    const int WN = D_ * D_;
    __hip_bfloat16* WtHG = Wt;
    __hip_bfloat16* WtQ  = Wt + (size_t)WN;
    __hip_bfloat16* WtK  = Wt + (size_t)2 * WN;
    __hip_bfloat16* WtV  = Wt + (size_t)3 * WN;
    __hip_bfloat16* WtO  = Wt + (size_t)4 * WN;

    // -------- Phase 0: weights (one dispatch) -------------------------------
    wt_transpose_kernel<<<dim3(8, 8, 5), 256, 0, stream>>>(W_hg, WQ, WK, WV, WO, Wt);

    // -------- Phase 1: hypergraph conv, all modalities batched --------------
    cvt3_kernel<<<dim3((unsigned)(BND_ / 256), 1, 3), 256, 0, stream>>>(x0, x1, x2, Xc);
    zero_kernel<<<(zeroWords + 255) / 256, 256, 0, stream>>>((float*)(ws + oZero), zeroWords);
    hg_count_kernel<<<dim3(C_ / 256, 1, 3), 256, 0, stream>>>(h0, h1, h2, Ddeg, Edeg);
    hg_scan_kernel<<<dim3(1, 1, 3), N_, 0, stream>>>(Ddeg, NOffs, Dinv, NCnt, N_);
    hg_scan_kernel<<<dim3(1, 1, 3), M_, 0, stream>>>(Edeg, EOffs, Bnorm, ECnt, M_);
    hg_fill_kernel<<<dim3(C_ / 256, 1, 3), 256, 0, stream>>>(h0, h1, h2, NOffs, EOffs,
                                                             NCnt, ECnt, NOrd, EOrd);
    launch_gemm(stream, dim3(BN_ / 128, D_ / 128, 3),
                Xc, Xc, D_, BND_, WtHG, WtHG, D_, 0,
                Xp, D_, BND_, 0, 0, D_, D_, 3,
                1.0f, nullptr, nullptr, nullptr, 1);
    hg_s12_kernel<<<dim3(BN_, 1, 3), 64, 0, stream>>>((const unsigned short*)Xp, att_hg, S1f, S2f);
    hg_edge_s2_kernel<<<dim3(M_, 1, 3), 256, 0, stream>>>(h0, h1, h2, EOffs, EOrd, S2f, Es2);
    hg_node_softmax_kernel<<<dim3(N_, 1, 3), 256, 0, stream>>>(h0, h1, h2, NOffs, NOrd,
                                                               S1f, Es2, EE, Inv);
    hg_pack_kernel<<<dim3(C_ * 16 / 256, 1, 3), 256, 0, stream>>>(h0, h1, h2, NOrd, EOrd,
                                                                  EE, Inv, EmS, NnS, CoefN, CoefE);
    hg_xedge_kernel<<<dim3(M_ * B_, 1, 3), 256, 0, stream>>>(EOffs, NnS, CoefE,
                                                             (const unsigned short*)Xp, Bnorm, Xe);
    hg_xnode_kernel<<<dim3(N_ * B_, 1, 3), 256, 0, stream>>>(NOffs, EmS, CoefN, Xe, Dinv, Hbf);

    // -------- Phase 2: K, V, Q for all 3 modalities -------------------------
    launch_gemm(stream, dim3(3 * BN_ / 128, D_ / 128, 1),
                Hbf, Hbf, D_, 0, WtK, WtK, D_, 0,
                Kall, D_, 0, 0, 0, D_, D_, 1,
                1.0f, bK, nullptr, nullptr, 1);
    launch_gemm(stream, dim3(3 * BN_ / 128, D_ / 128, 1),
                Hbf, Hbf, D_, 0, WtV, WtV, D_, 0,
                Vtmp, D_, 0, 0, 0, D_, D_, 1,
                1.0f, bV, nullptr, nullptr, 1);
    transpose_bf16_kernel<<<dim3(N_ / 32, D_ / 32, 48), 256, 0, stream>>>(
        Vtmp, Vt, N_, D_, (long long)N_ * D_, (long long)D_ * N_);
    launch_gemm(stream, dim3(3 * BN_ / 128, D_ / 128, 1),
                Hbf, Hbf, D_, 0, WtQ, WtQ, D_, 0,
                Qall, D_, 0, 0, 0, D_, D_, 1,
                0.0625f, bQ, nullptr, nullptr, 4);

    // -------- Phase 3: fused flash attention + output -----------------------
    flash_attn_kernel<<<dim3(N_ / 64, B_, 3), 256, 0, stream>>>(Qall, Kall, Vt, Msg);
    launch_gemm(stream, dim3(BN_ / 128, D_ / 128, 3),
                Hbf, Hbf, D_, BND_, WtO, WtO, D_, 0,
                outp, D_, BND_, 0, 0, D_, D_, 3,
                1.0f, bO, Msg, Msg + (size_t)3 * BND_, 2);
}